// Round 3
// baseline (139.733 us; speedup 1.0000x reference)
//
#include <hip/hip_runtime.h>
#include <hip/hip_cooperative_groups.h>

namespace cg = cooperative_groups;

#define NUM_CLASS 121
#define BROWS 262144
#define THREADS 256
#define BLOCKS (BROWS / THREADS)   // 1024 blocks * 4 waves = 4096 waves = 16/CU -> co-resident

// Single cooperative kernel:
//  phase 1: one thread per row, 5-tap weighted -log gather, block-reduce,
//           plain store of one partial per block into d_ws.
//  grid sync.
//  phase 2: block 0 reduces the 1024 partials and stores the scaled scalar.
__global__ __launch_bounds__(THREADS)
void sce_fused(const float* __restrict__ pred,
               const int*   __restrict__ label,
               const float* __restrict__ kw,
               float*       __restrict__ partial,
               float*       __restrict__ out) {
    const int row = blockIdx.x * THREADS + threadIdx.x;   // grid covers BROWS exactly

    const float w0 = kw[0], w1 = kw[1], w2 = kw[2], w3 = kw[3], w4 = kw[4];
    const float w[5] = {w0, w1, w2, w3, w4};

    const int lab = label[row];
    const float* __restrict__ p = pred + (size_t)row * NUM_CLASS;

    float acc = 0.0f;
    #pragma unroll
    for (int j = 0; j < 5; ++j) {
        const int  c  = lab + j - 2;
        const bool ok = (c >= 0) & (c < NUM_CLASS);
        const int  cc = ok ? c : 0;          // clamped: load always executes, in-bounds
        const float wj = ok ? w[j] : 0.0f;   // predicated weight, no divergence
        acc -= wj * __logf(p[cc] + 1e-8f);   // fast log: v_log_f32, ~2^-21 rel err
    }

    // wave-64 butterfly reduce
    #pragma unroll
    for (int off = 32; off > 0; off >>= 1)
        acc += __shfl_down(acc, off, 64);

    __shared__ float wsum[THREADS / 64];
    const int lane = threadIdx.x & 63;
    const int wid  = threadIdx.x >> 6;
    if (lane == 0) wsum[wid] = acc;
    __syncthreads();

    if (threadIdx.x == 0) {
        partial[blockIdx.x] = wsum[0] + wsum[1] + wsum[2] + wsum[3];
        __threadfence();                     // device-scope: visible across XCDs
    }

    cg::this_grid().sync();

    if (blockIdx.x == 0) {
        float a = 0.0f;
        #pragma unroll
        for (int i = threadIdx.x; i < BLOCKS; i += THREADS)
            a += partial[i];

        #pragma unroll
        for (int off = 32; off > 0; off >>= 1)
            a += __shfl_down(a, off, 64);

        __shared__ float wsum2[THREADS / 64];
        if (lane == 0) wsum2[wid] = a;
        __syncthreads();

        if (threadIdx.x == 0) {
            const float s = wsum2[0] + wsum2[1] + wsum2[2] + wsum2[3];
            out[0] = s * (1.0f / ((float)BROWS * (float)NUM_CLASS));
        }
    }
}

extern "C" void kernel_launch(void* const* d_in, const int* in_sizes, int n_in,
                              void* d_out, int out_size, void* d_ws, size_t ws_size,
                              hipStream_t stream) {
    const float* pred  = (const float*)d_in[0];
    const int*   label = (const int*)d_in[1];
    const float* kw    = (const float*)d_in[2];
    float*       out   = (float*)d_out;
    float*       part  = (float*)d_ws;       // 1024 floats = 4 KiB of scratch

    void* args[] = {(void*)&pred, (void*)&label, (void*)&kw, (void*)&part, (void*)&out};
    hipLaunchCooperativeKernel((const void*)sce_fused, dim3(BLOCKS), dim3(THREADS),
                               args, 0, stream);
}

// Round 4
// 12.821 us; speedup vs baseline: 10.8990x; 10.8990x over previous
//
#include <hip/hip_runtime.h>

#define NUM_CLASS 121
#define BROWS 262144
#define THREADS 256
#define BLOCKS (BROWS / THREADS)          // 1024
#define TOTAL (BROWS * NUM_CLASS)          // 31719424 < 2^31

// Kernel 1: one thread per row.
// The 5 taps pred[row, lab-2 .. lab+2] (clipped to [0,121)) always lie inside
// the 8-float ALIGNED flat window starting at ga = clamp((row*121+lab-2)&~3,
// 0, TOTAL-8). Load that window as two float4 (2 VMEM transactions/lane
// instead of 5), then apply predicated weights per window slot.
__global__ __launch_bounds__(THREADS)
void sce_partial(const float* __restrict__ pred,
                 const int*   __restrict__ label,
                 const float* __restrict__ kw,
                 float*       __restrict__ partial) {
    const int row = blockIdx.x * THREADS + threadIdx.x;   // grid covers BROWS exactly

    const float w0 = kw[0], w1 = kw[1], w2 = kw[2], w3 = kw[3], w4 = kw[4];

    const int lab  = label[row];
    const int base = row * NUM_CLASS;
    const int g    = base + lab - 2;       // flat index of tap j=0 (may be base-2)
    int ga = g & ~3;                       // 16B-aligned window start
    ga = ga < 0 ? 0 : ga;
    ga = ga > (TOTAL - 8) ? (TOTAL - 8) : ga;   // both clamps keep ga % 4 == 0

    const float4 q0 = *reinterpret_cast<const float4*>(pred + ga);
    const float4 q1 = *reinterpret_cast<const float4*>(pred + ga + 4);
    const float v[8] = {q0.x, q0.y, q0.z, q0.w, q1.x, q1.y, q1.z, q1.w};

    float acc = 0.0f;
    #pragma unroll
    for (int i = 0; i < 8; ++i) {          // i is compile-time after unroll
        const int j = (ga - g) + i;        // tap index; valid taps are 0..4
        const int c = (ga - base) + i;     // class index of this window slot
        const bool ok = (j >= 0) & (j < 5) & (c >= 0) & (c < NUM_CLASS);
        float wj = (j <= 0) ? w0 : (j == 1) ? w1 : (j == 2) ? w2
                 : (j == 3) ? w3 : w4;     // cndmask chain, no memory
        wj = ok ? wj : 0.0f;
        acc -= wj * __logf(v[i] + 1e-8f);  // v_log_f32: ~2^-21 rel err (validated R3)
    }

    // wave-64 butterfly reduce
    #pragma unroll
    for (int off = 32; off > 0; off >>= 1)
        acc += __shfl_down(acc, off, 64);

    __shared__ float wsum[THREADS / 64];
    const int lane = threadIdx.x & 63;
    const int wid  = threadIdx.x >> 6;
    if (lane == 0) wsum[wid] = acc;
    __syncthreads();

    if (threadIdx.x == 0)
        partial[blockIdx.x] = wsum[0] + wsum[1] + wsum[2] + wsum[3];
}

// Kernel 2: single block reduces BLOCKS partials, scales, stores the scalar.
__global__ __launch_bounds__(THREADS)
void sce_reduce(const float* __restrict__ partial,
                float*       __restrict__ out) {
    float acc = 0.0f;
    #pragma unroll
    for (int i = threadIdx.x; i < BLOCKS; i += THREADS)
        acc += partial[i];

    #pragma unroll
    for (int off = 32; off > 0; off >>= 1)
        acc += __shfl_down(acc, off, 64);

    __shared__ float wsum[THREADS / 64];
    const int lane = threadIdx.x & 63;
    const int wid  = threadIdx.x >> 6;
    if (lane == 0) wsum[wid] = acc;
    __syncthreads();

    if (threadIdx.x == 0) {
        const float s = wsum[0] + wsum[1] + wsum[2] + wsum[3];
        out[0] = s * (1.0f / ((float)BROWS * (float)NUM_CLASS));
    }
}

extern "C" void kernel_launch(void* const* d_in, const int* in_sizes, int n_in,
                              void* d_out, int out_size, void* d_ws, size_t ws_size,
                              hipStream_t stream) {
    const float* pred  = (const float*)d_in[0];
    const int*   label = (const int*)d_in[1];
    const float* kw    = (const float*)d_in[2];
    float*       out   = (float*)d_out;
    float*       part  = (float*)d_ws;       // 1024 floats = 4 KiB scratch

    sce_partial<<<BLOCKS, THREADS, 0, stream>>>(pred, label, kw, part);
    sce_reduce<<<1, THREADS, 0, stream>>>(part, out);
}